// Round 2
// baseline (597.866 us; speedup 1.0000x reference)
//
#include <hip/hip_runtime.h>

// Problem constants
#define BB   4
#define CIN  64
#define HH   256
#define WW   256
#define QQ   256
#define KK   16

typedef _Float16 half8 __attribute__((ext_vector_type(8)));
typedef float   f32x16 __attribute__((ext_vector_type(16)));
typedef unsigned int u32;

// ---- workspace layout (bytes); r8 proved ws_size >= 169378048 ----
#define OFF_W1R   0ull
#define OFF_W2R   294912ull
#define OFF_WMU   1474560ull
#define OFF_LGB   1490944ull
#define OFF_ACT0  1605888ull
#define OFF_ACT1  35160320ull

__device__ __forceinline__ void dma16(const void* g, void* l) {
  __builtin_amdgcn_global_load_lds(
      (const __attribute__((address_space(1))) u32*)g,
      (__attribute__((address_space(3))) u32*)l, 16, 0, 0);
}

// ---------------------------------------------------------------------------
// Prep. Blocks 0..575: w1r; 576..2879: w2r; 2880..3007: wmu2 partials;
// 3008..3023: lgb. Weight image block (cc,tt)=16KB: 256 rows x 32ch;
// 16B-quarter q of row n stored at slot q^((n>>1)&3).
// ---------------------------------------------------------------------------
__global__ __launch_bounds__(256) void k_prep(
    const float* __restrict__ w1, const float* __restrict__ w2,
    const float* __restrict__ w3, const float* __restrict__ b3,
    const float* __restrict__ mu,
    _Float16* __restrict__ w1r, _Float16* __restrict__ w2r,
    float* __restrict__ wpart, float* __restrict__ lgb) {
  int bid = blockIdx.x, tid = threadIdx.x;
  if (bid < 576) {                          // w1r (CI=64)
    int idx = bid * 256 + tid;
    int blk = idx >> 13;
    int cc = blk / 9, tt = blk - cc * 9;
    int rem = idx & 8191;
    int n = rem >> 5, r = rem & 31;
    int q = (r >> 3) ^ ((n >> 1) & 3), e = r & 7;
    int c = cc * 32 + q * 8 + e;
    w1r[idx] = (_Float16)w1[(n * 64 + c) * 9 + tt];
  } else if (bid < 2880) {                  // w2r (CI=256)
    int d = (bid - 576) * 256 + tid;
    int blk = d >> 13;
    int cc = blk / 9, tt = blk - cc * 9;
    int rem = d & 8191;
    int n = rem >> 5, r = rem & 31;
    int q = (r >> 3) ^ ((n >> 1) & 3), e = r & 7;
    int c = cc * 32 + q * 8 + e;
    w2r[d] = (_Float16)w2[(n * 256 + c) * 9 + tt];
  } else if (bid < 3008) {                  // wmu2 partials
    int j = bid - 2880;
    int k = j >> 3, o0 = (j & 7) << 5;
    float s = 0.f;
#pragma unroll 4
    for (int oi = 0; oi < 32; ++oi) {
      int o = o0 + oi;
      s = fmaf(mu[k * 256 + o], w3[o * 256 + tid], s);
    }
    wpart[j * 256 + tid] = s;
  } else {                                  // lgb, one block per k
    int k = bid - 3008;
    float m = mu[k * 256 + tid];
    __shared__ float red[256];
    red[tid] = m * (2.f * b3[tid] - m);
    __syncthreads();
    for (int st = 128; st > 0; st >>= 1) {
      if (tid < st) red[tid] += red[tid + st];
      __syncthreads();
    }
    if (tid == 0) lgb[k] = red[0];
  }
}

// Reduce wmu2 partials: wmu2[k][c] = 2 * sum_p wpart[k*8+p][c]. 16 blocks.
__global__ __launch_bounds__(256) void k_prep2(
    const float* __restrict__ wpart, float* __restrict__ wmu2) {
  int k = blockIdx.x, tid = threadIdx.x;
  float s = 0.f;
#pragma unroll
  for (int p = 0; p < 8; ++p) s += wpart[(k * 8 + p) * 256 + tid];
  wmu2[k * 256 + tid] = 2.f * s;
}

// ---------------------------------------------------------------------------
// T0: x NCHW fp32 -> act0 [b][HW][64] fp16, all 4 batches. grid 4096.
// ---------------------------------------------------------------------------
__global__ __launch_bounds__(256) void k_t0(const float* __restrict__ x,
                                            _Float16* __restrict__ act0) {
  __shared__ float tile[64][65];
  int blk = blockIdx.x;
  int b = blk >> 10;
  int p0 = (blk & 1023) << 6;
  int t = threadIdx.x;
  {
    int p = t & 63, c0 = t >> 6;
    const float* xb = x + (size_t)b * (CIN * 65536) + p0 + p;
#pragma unroll
    for (int i = 0; i < 16; ++i) {
      int c = c0 + (i << 2);
      tile[c][p] = xb[(size_t)c * 65536];
    }
  }
  __syncthreads();
  {
    _Float16* o = act0 + (size_t)(b * 65536 + p0) * CIN;
#pragma unroll
    for (int uu = 0; uu < 2; ++uu) {
      int u = t + (uu << 8);
      int px = u & 63, oct = u >> 6;
      half8 h;
#pragma unroll
      for (int i = 0; i < 8; ++i) h[i] = (_Float16)tile[oct * 8 + i][px];
      *(half8*)(o + px * CIN + oct * 8) = h;
    }
  }
}

// ---------------------------------------------------------------------------
// Conv 3x3 (replicate pad) + bias + ReLU, 32x32x16 fp16 MFMA.
//
// Phase-pipelined schedule (this round): each tap = two K-phases (ks0/ks1,
// 8 MFMA each). Steady rhythm per phase: issue 6 ds_reads for the NEXT
// phase, run 8 MFMA on fragments read LAST phase -> LDS-read latency is
// off the MFMA critical path. One barrier per tap, placed MID-tap (end of
// ph0): with lgkmcnt(0) it is the WAR guard letting ph1 re-DMA buffer
// t%3 as B[t+3] ((t+3)%3==t%3, 9%3==0 keeps indices compile-time), and
// with vmcnt(4) it is the landing guard for B[t+1] (issued 1.5 taps ago).
// A is double-buffered; A[cc+1] DMA'd at ph1 of t==6 (retired by the
// t==8 sync). vmcnt: 4 normally; 7 at t==7 when A in flight; 0 in the
// last-cc drain. Register cost unchanged vs previous round (12 half8
// fragments, statically named set0=ks0 / set1=ks1).
// Epilogue: stage C-tile in LDS [px][264] fp16, coalesced dwordx4 stores.
// grid 512*NB; b = blockIdx>>9.
// ---------------------------------------------------------------------------
template <int CI>
__global__ __launch_bounds__(256, 2) void k_conv(
    const _Float16* __restrict__ actin, const char* __restrict__ wr,
    const float* __restrict__ bias, _Float16* __restrict__ actout) {
  constexpr int NC = CI / 32;
  constexpr int NT = 9 * NC;
  __shared__ __align__(16) char smem[73728];   // As(2x12288)+Bs(3x16384) | Qs
  auto As = (char(*)[12288])smem;
  _Float16* Qs = (_Float16*)smem;              // [128][264] fp16 (epilogue)

  int tid = threadIdx.x;
  int b = blockIdx.x >> 9;
  int tile = blockIdx.x & 511;
  int txi = tile & 15, tyi = tile >> 4;
  int x0 = txi << 4, y0 = tyi << 3;
  int lane = tid & 63, wave = tid >> 6;
  int mwave = wave >> 1, nwave = wave & 1;
  int l31 = lane & 31, khalf = lane >> 5;

  f32x16 acc[2][4];
#pragma unroll
  for (int s = 0; s < 2; ++s)
#pragma unroll
    for (int nt = 0; nt < 4; ++nt)
#pragma unroll
      for (int r = 0; r < 16; ++r) acc[s][nt][r] = 0.f;

  const char* aG[3];
  int aL[3];
#pragma unroll
  for (int i = 0; i < 3; ++i) {
    int px = (wave * 3 + i) * 16 + (lane >> 2);
    int s = lane & 3;
    int pxc = min(px, 179);
    int hy = pxc / 18, hx = pxc - hy * 18;
    int y = min(max(y0 - 1 + hy, 0), 255);
    int x = min(max(x0 - 1 + hx, 0), 255);
    int q = s ^ ((pxc >> 1) & 3);
    aG[i] = (const char*)actin +
            (((size_t)(b * 65536 + y * 256 + x)) * CI + q * 8) * 2;
    aL[i] = (wave * 3 + i) * 1024;
  }
  const char* bG = wr + wave * 4096 + lane * 16;
  int bL = wave * 4096;

  // B fragment byte offsets (ks0); ks1 = bo ^ 32.
  int bo[4];
#pragma unroll
  for (int nt = 0; nt < 4; ++nt) {
    int n = nwave * 128 + nt * 32 + l31;
    bo[nt] = n * 64 + ((khalf << 4) ^ (((n >> 1) & 3) << 4));
  }
  int pxA = (mwave * 4 + (l31 >> 4)) * 18 + (l31 & 15);

  // -------- prologue: A(cc=0) + B tiles 0,1,2; retire A,B0,B1; keep B2.
#pragma unroll
  for (int i = 0; i < 3; ++i) dma16(aG[i], &As[0][aL[i]]);
#pragma unroll
  for (int bufi = 0; bufi < 3; ++bufi)
#pragma unroll
    for (int i = 0; i < 4; ++i)
      dma16(bG + bufi * 16384 + i * 1024,
            smem + 24576 + bufi * 16384 + bL + i * 1024);
  asm volatile("s_waitcnt vmcnt(4)" ::: "memory");
  __builtin_amdgcn_s_barrier();

  half8 af0[2], af1[2], bf0[4], bf1[4];
  // read set0 (ks0 of tap 0)
  {
    const char* Ab = As[0];
    const char* Bb = smem + 24576;
#pragma unroll
    for (int s = 0; s < 2; ++s) {
      int px = pxA + s * 36;
      int a = px * 64 + ((khalf << 4) ^ (((px >> 1) & 3) << 4));
      af0[s] = *(const half8*)(Ab + a);
    }
#pragma unroll
    for (int nt = 0; nt < 4; ++nt) bf0[nt] = *(const half8*)(Bb + bo[nt]);
  }

  for (int cc = 0; cc < NC; ++cc) {
    const char* Ab = As[cc & 1];
    const char* Abn = As[(cc + 1) & 1];
#pragma unroll
    for (int t = 0; t < 9; ++t) {
      int j = cc * 9 + t;
      const char* Bb = smem + 24576 + (t % 3) * 16384;
      const char* Bbn = smem + 24576 + ((t + 1) % 3) * 16384;
      int D = (t / 3) * 18 + (t % 3);
      // ---- ph0: read set1 (ks1, tap t), MFMA set0 ----
#pragma unroll
      for (int s = 0; s < 2; ++s) {
        int px = pxA + s * 36 + D;
        int a = px * 64 + ((((2 + khalf)) << 4) ^ (((px >> 1) & 3) << 4));
        af1[s] = *(const half8*)(Ab + a);
      }
#pragma unroll
      for (int nt = 0; nt < 4; ++nt)
        bf1[nt] = *(const half8*)(Bb + (bo[nt] ^ 32));
      __builtin_amdgcn_s_setprio(1);
#pragma unroll
      for (int s = 0; s < 2; ++s)
#pragma unroll
        for (int nt = 0; nt < 4; ++nt)
          acc[s][nt] = __builtin_amdgcn_mfma_f32_32x32x16_f16(
              af0[s], bf0[nt], acc[s][nt], 0, 0, 0);
      __builtin_amdgcn_s_setprio(0);
      // ---- mid-tap sync: retire B[t+1] (and A at t==8); keep newest.
      if (t <= 6) {
        asm volatile("s_waitcnt vmcnt(4) lgkmcnt(0)" ::: "memory");
      } else if (t == 7) {
        if (cc + 1 < NC)
          asm volatile("s_waitcnt vmcnt(7) lgkmcnt(0)" ::: "memory");
        else
          asm volatile("s_waitcnt vmcnt(0) lgkmcnt(0)" ::: "memory");
      } else {
        if (cc + 1 < NC)
          asm volatile("s_waitcnt vmcnt(4) lgkmcnt(0)" ::: "memory");
        else
          asm volatile("s_waitcnt vmcnt(0) lgkmcnt(0)" ::: "memory");
      }
      __builtin_amdgcn_s_barrier();
      // ---- ph1: DMA (A at t==6; B[t+3] into buffer t%3), read set0
      //          (ks0 of tap t+1), MFMA set1 ----
      if (t == 6 && cc + 1 < NC) {
#pragma unroll
        for (int i = 0; i < 3; ++i)
          dma16(aG[i] + (cc + 1) * 64, &As[(cc + 1) & 1][aL[i]]);
      }
      if (j + 3 < NT) {
        const char* bsrc = bG + (size_t)(j + 3) * 16384;
        char* bdst = smem + 24576 + (t % 3) * 16384 + bL;
#pragma unroll
        for (int i = 0; i < 4; ++i) dma16(bsrc + i * 1024, bdst + i * 1024);
      }
      if (j + 1 < NT) {
        const char* An = (t < 8) ? Ab : Abn;
        int Dn = (t < 8) ? (((t + 1) / 3) * 18 + ((t + 1) % 3)) : 0;
#pragma unroll
        for (int s = 0; s < 2; ++s) {
          int px = pxA + s * 36 + Dn;
          int a = px * 64 + ((khalf << 4) ^ (((px >> 1) & 3) << 4));
          af0[s] = *(const half8*)(An + a);
        }
#pragma unroll
        for (int nt = 0; nt < 4; ++nt)
          bf0[nt] = *(const half8*)(Bbn + bo[nt]);
      }
      __builtin_amdgcn_s_setprio(1);
#pragma unroll
      for (int s = 0; s < 2; ++s)
#pragma unroll
        for (int nt = 0; nt < 4; ++nt)
          acc[s][nt] = __builtin_amdgcn_mfma_f32_32x32x16_f16(
              af1[s], bf1[nt], acc[s][nt], 0, 0, 0);
      __builtin_amdgcn_s_setprio(0);
      // no tap-end sync: next ph0's fragments were read above; buffers
      // touched next tap are guarded by that tap's mid-tap barrier.
    }
  }

  // ---- epilogue: bias+relu, stage to LDS [px][264], coalesced stores ----
  // C/D: col = lane&31, row = (r&3) + 8*(r>>2) + 4*(lane>>5)
#pragma unroll
  for (int s = 0; s < 2; ++s)
#pragma unroll
    for (int nt = 0; nt < 4; ++nt) {
      int n = nwave * 128 + nt * 32 + l31;
      float bn = bias[n];
#pragma unroll
      for (int r = 0; r < 16; ++r) {
        int mrow = (r & 3) + 8 * (r >> 2) + 4 * khalf;
        int p = (mwave * 4 + s * 2 + (mrow >> 4)) * 16 + (mrow & 15);
        Qs[p * 264 + n] = (_Float16)fmaxf(acc[s][nt][r] + bn, 0.f);
      }
    }
  __syncthreads();
  {
    _Float16* gout = actout + (((size_t)(b * 65536 + y0 * 256 + x0)) << 8);
#pragma unroll
    for (int i = 0; i < 16; ++i) {
      int f = tid + (i << 8);
      int p = f >> 5, o = f & 31;
      half8 v = *(const half8*)&Qs[p * 264 + o * 8];
      *(half8*)(gout + (((p >> 4) * 256 + (p & 15)) << 8) + o * 8) = v;
    }
  }
}

// ---------------------------------------------------------------------------
// Head, all 4 batches in one dispatch. One px per thread, all fp32 VALU;
// wmu2/lgb/label wave-uniform -> scalar loads. grid 1024.
// ---------------------------------------------------------------------------
__global__ __launch_bounds__(256) void k_head(
    const _Float16* __restrict__ a2_0, const _Float16* __restrict__ a2_1,
    const _Float16* __restrict__ a2_2, const _Float16* __restrict__ a2_3,
    const float* __restrict__ wmu2, const float* __restrict__ lgb,
    const float* __restrict__ label, float* __restrict__ out) {
  int b = blockIdx.x >> 8;
  int px = (blockIdx.x & 255) * 256 + threadIdx.x;
  const _Float16* base = (b == 0) ? a2_0 : (b == 1) ? a2_1
                       : (b == 2) ? a2_2 : a2_3;
  const half8* ap = (const half8*)(base + ((size_t)px << 8));
  float cr[16];
#pragma unroll
  for (int k = 0; k < 16; ++k) cr[k] = lgb[k];
#pragma unroll 2
  for (int cc = 0; cc < 32; ++cc) {
    half8 h = ap[cc];
    float a0 = (float)h[0], a1 = (float)h[1], a2 = (float)h[2],
          a3 = (float)h[3], a4 = (float)h[4], a5 = (float)h[5],
          a6 = (float)h[6], a7 = (float)h[7];
#pragma unroll
    for (int k = 0; k < 16; ++k) {
      const float* w = wmu2 + (k << 8) + (cc << 3);
      float c0 = cr[k];
      c0 = fmaf(a0, w[0], c0);
      c0 = fmaf(a1, w[1], c0);
      c0 = fmaf(a2, w[2], c0);
      c0 = fmaf(a3, w[3], c0);
      c0 = fmaf(a4, w[4], c0);
      c0 = fmaf(a5, w[5], c0);
      c0 = fmaf(a6, w[6], c0);
      c0 = fmaf(a7, w[7], c0);
      cr[k] = c0;
    }
  }
  float mx = cr[0];
#pragma unroll
  for (int k = 1; k < 16; ++k) mx = fmaxf(mx, cr[k]);
  float num = 0.f, den = 0.f;
#pragma unroll
  for (int k = 0; k < 16; ++k) {
    float e = __expf(cr[k] - mx);
    num = fmaf(e, label[k], num);
    den += e;
  }
  out[(size_t)b * 65536 + px] = num / den;
}

// ---------------------------------------------------------------------------
extern "C" void kernel_launch(void* const* d_in, const int* in_sizes, int n_in,
                              void* d_out, int out_size, void* d_ws, size_t ws_size,
                              hipStream_t stream) {
  const float* x  = (const float*)d_in[0];
  const float* w1 = (const float*)d_in[1];
  const float* b1 = (const float*)d_in[2];
  const float* w2 = (const float*)d_in[3];
  const float* b2 = (const float*)d_in[4];
  const float* w3 = (const float*)d_in[5];
  const float* b3 = (const float*)d_in[6];
  const float* mu = (const float*)d_in[7];
  const float* label = (const float*)d_in[8];
  float* out = (float*)d_out;

  char* ws = (char*)d_ws;
  _Float16* w1r  = (_Float16*)(ws + OFF_W1R);
  _Float16* w2r  = (_Float16*)(ws + OFF_W2R);
  float*    wmu2 = (float*)   (ws + OFF_WMU);
  float*    lgb  = (float*)   (ws + OFF_LGB);
  _Float16* act0 = (_Float16*)(ws + OFF_ACT0);   // [4][HW][64], 32 MB
  _Float16* act1 = (_Float16*)(ws + OFF_ACT1);   // [4][HW][256], 128 MB
  float*    wpart = (float*)  (ws + OFF_ACT1);   // 131 KB, dead before conv1

  _Float16* a2d[4] = {
    (_Float16*)(ws + OFF_ACT0),
    act1 + 0 * (size_t)65536 * 256,
    act1 + 1 * (size_t)65536 * 256,
    act1 + 2 * (size_t)65536 * 256
  };

  k_prep<<<3024, 256, 0, stream>>>(w1, w2, w3, b3, mu, w1r, w2r, wpart, lgb);
  k_prep2<<<16, 256, 0, stream>>>(wpart, wmu2);
  k_t0<<<4096, 256, 0, stream>>>(x, act0);
  k_conv<64><<<2048, 256, 0, stream>>>(act0, (const char*)w1r, b1, act1);
  for (int b = 0; b < BB; ++b)
    k_conv<256><<<512, 256, 0, stream>>>(act1 + (size_t)b * 65536 * 256,
                                         (const char*)w2r, b2, a2d[b]);
  k_head<<<1024, 256, 0, stream>>>(a2d[0], a2d[1], a2d[2], a2d[3],
                                   wmu2, lgb, label, out);
}

// Round 3
// 571.268 us; speedup vs baseline: 1.0466x; 1.0466x over previous
//
#include <hip/hip_runtime.h>

// Problem constants
#define BB   4
#define CIN  64
#define HH   256
#define WW   256
#define QQ   256
#define KK   16

typedef _Float16 half8 __attribute__((ext_vector_type(8)));
typedef float   f32x16 __attribute__((ext_vector_type(16)));
typedef unsigned int u32;

// ---- workspace layout (bytes); r8 proved ws_size >= 169378048 ----
#define OFF_W1R   0ull
#define OFF_W2R   294912ull
#define OFF_WMU   1474560ull
#define OFF_LGB   1490944ull
#define OFF_ACT0  1605888ull
#define OFF_ACT1  35160320ull

__device__ __forceinline__ void dma16(const void* g, void* l) {
  __builtin_amdgcn_global_load_lds(
      (const __attribute__((address_space(1))) u32*)g,
      (__attribute__((address_space(3))) u32*)l, 16, 0, 0);
}

// ---------------------------------------------------------------------------
// Prep. Blocks 0..575: w1r; 576..2879: w2r; 2880..3007: wmu2 partials;
// 3008..3023: lgb. Weight image block (cc,tt)=16KB: 256 rows x 32ch;
// 16B-quarter q of row n stored at slot q^((n>>1)&3).
// ---------------------------------------------------------------------------
__global__ __launch_bounds__(256) void k_prep(
    const float* __restrict__ w1, const float* __restrict__ w2,
    const float* __restrict__ w3, const float* __restrict__ b3,
    const float* __restrict__ mu,
    _Float16* __restrict__ w1r, _Float16* __restrict__ w2r,
    float* __restrict__ wpart, float* __restrict__ lgb) {
  int bid = blockIdx.x, tid = threadIdx.x;
  if (bid < 576) {                          // w1r (CI=64)
    int idx = bid * 256 + tid;
    int blk = idx >> 13;
    int cc = blk / 9, tt = blk - cc * 9;
    int rem = idx & 8191;
    int n = rem >> 5, r = rem & 31;
    int q = (r >> 3) ^ ((n >> 1) & 3), e = r & 7;
    int c = cc * 32 + q * 8 + e;
    w1r[idx] = (_Float16)w1[(n * 64 + c) * 9 + tt];
  } else if (bid < 2880) {                  // w2r (CI=256)
    int d = (bid - 576) * 256 + tid;
    int blk = d >> 13;
    int cc = blk / 9, tt = blk - cc * 9;
    int rem = d & 8191;
    int n = rem >> 5, r = rem & 31;
    int q = (r >> 3) ^ ((n >> 1) & 3), e = r & 7;
    int c = cc * 32 + q * 8 + e;
    w2r[d] = (_Float16)w2[(n * 256 + c) * 9 + tt];
  } else if (bid < 3008) {                  // wmu2 partials
    int j = bid - 2880;
    int k = j >> 3, o0 = (j & 7) << 5;
    float s = 0.f;
#pragma unroll 4
    for (int oi = 0; oi < 32; ++oi) {
      int o = o0 + oi;
      s = fmaf(mu[k * 256 + o], w3[o * 256 + tid], s);
    }
    wpart[j * 256 + tid] = s;
  } else {                                  // lgb, one block per k
    int k = bid - 3008;
    float m = mu[k * 256 + tid];
    __shared__ float red[256];
    red[tid] = m * (2.f * b3[tid] - m);
    __syncthreads();
    for (int st = 128; st > 0; st >>= 1) {
      if (tid < st) red[tid] += red[tid + st];
      __syncthreads();
    }
    if (tid == 0) lgb[k] = red[0];
  }
}

// Reduce wmu2 partials: wmu2[k][c] = 2 * sum_p wpart[k*8+p][c]. 16 blocks.
__global__ __launch_bounds__(256) void k_prep2(
    const float* __restrict__ wpart, float* __restrict__ wmu2) {
  int k = blockIdx.x, tid = threadIdx.x;
  float s = 0.f;
#pragma unroll
  for (int p = 0; p < 8; ++p) s += wpart[(k * 8 + p) * 256 + tid];
  wmu2[k * 256 + tid] = 2.f * s;
}

// ---------------------------------------------------------------------------
// T0: x NCHW fp32 -> act0 [b][HW][64] fp16, all 4 batches. grid 4096.
// ---------------------------------------------------------------------------
__global__ __launch_bounds__(256) void k_t0(const float* __restrict__ x,
                                            _Float16* __restrict__ act0) {
  __shared__ float tile[64][65];
  int blk = blockIdx.x;
  int b = blk >> 10;
  int p0 = (blk & 1023) << 6;
  int t = threadIdx.x;
  {
    int p = t & 63, c0 = t >> 6;
    const float* xb = x + (size_t)b * (CIN * 65536) + p0 + p;
#pragma unroll
    for (int i = 0; i < 16; ++i) {
      int c = c0 + (i << 2);
      tile[c][p] = xb[(size_t)c * 65536];
    }
  }
  __syncthreads();
  {
    _Float16* o = act0 + (size_t)(b * 65536 + p0) * CIN;
#pragma unroll
    for (int uu = 0; uu < 2; ++uu) {
      int u = t + (uu << 8);
      int px = u & 63, oct = u >> 6;
      half8 h;
#pragma unroll
      for (int i = 0; i < 8; ++i) h[i] = (_Float16)tile[oct * 8 + i][px];
      *(half8*)(o + px * CIN + oct * 8) = h;
    }
  }
}

// ---------------------------------------------------------------------------
// Conv 3x3 (replicate pad) + bias + ReLU, 32x32x16 fp16 MFMA.
//
// Phase-pipelined + PINNED schedule. Each tap = two K-phases (ks0/ks1,
// 8 MFMA each). Per phase: issue 2 JIT A ds_reads + 4 prefetch B ds_reads
// (for the NEXT phase), then sched_barrier(0) to forbid the scheduler
// sinking the prefetch below the MFMA cluster (r2 null: at the 256-reg
// cap hipcc sank prefetches to shrink live ranges -> serial execution).
// B frags double-named bfA/bfB (phase parity, no runtime indexing); A
// frags JIT (register diet: 40 frag VGPRs vs 48, leaves allocator slack).
// Sync skeleton unchanged from r2: one mid-tap barrier per tap with
// counted vmcnt (retire B[t+1], keep B[t+2] flying) + lgkmcnt(0) WAR
// guard for the ph1 DMA into buffer t%3. B triple-buffered, A double-
// buffered (A[cc+1] DMA at ph1 of t==6; retired by mid-barrier(8)'s
// vmcnt(4)). vmcnt table: t<=6: 4; t==7: 7 (more) / 0 (last); t==8:
// 4 (more) / 0 (last).
// Epilogue: __syncthreads (WAR: Qs overlays As/Bs), stage C-tile in LDS
// [px][264] fp16, coalesced dwordx4 stores. grid 512*NB; b = blockIdx>>9.
// ---------------------------------------------------------------------------
template <int CI>
__global__ __launch_bounds__(256, 2) void k_conv(
    const _Float16* __restrict__ actin, const char* __restrict__ wr,
    const float* __restrict__ bias, _Float16* __restrict__ actout) {
  constexpr int NC = CI / 32;
  constexpr int NT = 9 * NC;
  __shared__ __align__(16) char smem[73728];   // As(2x12288)+Bs(3x16384) | Qs
  auto As = (char(*)[12288])smem;
  _Float16* Qs = (_Float16*)smem;              // [128][264] fp16 (epilogue)

  int tid = threadIdx.x;
  int b = blockIdx.x >> 9;
  int tile = blockIdx.x & 511;
  int txi = tile & 15, tyi = tile >> 4;
  int x0 = txi << 4, y0 = tyi << 3;
  int lane = tid & 63, wave = tid >> 6;
  int mwave = wave >> 1, nwave = wave & 1;
  int l31 = lane & 31, khalf = lane >> 5;

  f32x16 acc[2][4];
#pragma unroll
  for (int s = 0; s < 2; ++s)
#pragma unroll
    for (int nt = 0; nt < 4; ++nt)
#pragma unroll
      for (int r = 0; r < 16; ++r) acc[s][nt][r] = 0.f;

  const char* aG[3];
  int aL[3];
#pragma unroll
  for (int i = 0; i < 3; ++i) {
    int px = (wave * 3 + i) * 16 + (lane >> 2);
    int s = lane & 3;
    int pxc = min(px, 179);
    int hy = pxc / 18, hx = pxc - hy * 18;
    int y = min(max(y0 - 1 + hy, 0), 255);
    int x = min(max(x0 - 1 + hx, 0), 255);
    int q = s ^ ((pxc >> 1) & 3);
    aG[i] = (const char*)actin +
            (((size_t)(b * 65536 + y * 256 + x)) * CI + q * 8) * 2;
    aL[i] = (wave * 3 + i) * 1024;
  }
  const char* bG = wr + wave * 4096 + lane * 16;
  int bL = wave * 4096;

  // B fragment byte offsets (ks0); ks1 = bo ^ 32.
  int bo[4];
#pragma unroll
  for (int nt = 0; nt < 4; ++nt) {
    int n = nwave * 128 + nt * 32 + l31;
    bo[nt] = n * 64 + ((khalf << 4) ^ (((n >> 1) & 3) << 4));
  }
  int pxA = (mwave * 4 + (l31 >> 4)) * 18 + (l31 & 15);

  // -------- prologue: A(cc=0) + B tiles 0,1,2; retire A,B0,B1; keep B2.
#pragma unroll
  for (int i = 0; i < 3; ++i) dma16(aG[i], &As[0][aL[i]]);
#pragma unroll
  for (int bufi = 0; bufi < 3; ++bufi)
#pragma unroll
    for (int i = 0; i < 4; ++i)
      dma16(bG + bufi * 16384 + i * 1024,
            smem + 24576 + bufi * 16384 + bL + i * 1024);
  asm volatile("s_waitcnt vmcnt(4)" ::: "memory");
  __builtin_amdgcn_s_barrier();

  half8 af[2], bfA[4], bfB[4];
  {  // prefetch bfA = ks0 of tap 0
    const char* Bb = smem + 24576;
#pragma unroll
    for (int nt = 0; nt < 4; ++nt) bfA[nt] = *(const half8*)(Bb + bo[nt]);
  }

  for (int cc = 0; cc < NC; ++cc) {
    const char* Ab = As[cc & 1];
    bool more = (cc + 1 < NC);
#pragma unroll
    for (int t = 0; t < 9; ++t) {
      int j = cc * 9 + t;
      const char* Bb = smem + 24576 + (t % 3) * 16384;
      int D = (t / 3) * 18 + (t % 3);
      // ---------------- ph0: JIT af(ks0), prefetch bfB(ks1), MFMA ks0 ----
#pragma unroll
      for (int s = 0; s < 2; ++s) {
        int px = pxA + s * 36 + D;
        int a = px * 64 + ((khalf << 4) ^ (((px >> 1) & 3) << 4));
        af[s] = *(const half8*)(Ab + a);
      }
#pragma unroll
      for (int nt = 0; nt < 4; ++nt)
        bfB[nt] = *(const half8*)(Bb + (bo[nt] ^ 32));
      __builtin_amdgcn_sched_barrier(0);
      __builtin_amdgcn_s_setprio(1);
#pragma unroll
      for (int s = 0; s < 2; ++s)
#pragma unroll
        for (int nt = 0; nt < 4; ++nt)
          acc[s][nt] = __builtin_amdgcn_mfma_f32_32x32x16_f16(
              af[s], bfA[nt], acc[s][nt], 0, 0, 0);
      __builtin_amdgcn_s_setprio(0);
      // ---- mid-tap sync: retire B[t+1] (and A at t==8); keep newest ----
      if (t <= 6) {
        asm volatile("s_waitcnt vmcnt(4) lgkmcnt(0)" ::: "memory");
      } else if (t == 7) {
        if (more)
          asm volatile("s_waitcnt vmcnt(7) lgkmcnt(0)" ::: "memory");
        else
          asm volatile("s_waitcnt vmcnt(0) lgkmcnt(0)" ::: "memory");
      } else {
        if (more)
          asm volatile("s_waitcnt vmcnt(4) lgkmcnt(0)" ::: "memory");
        else
          asm volatile("s_waitcnt vmcnt(0) lgkmcnt(0)" ::: "memory");
      }
      __builtin_amdgcn_s_barrier();
      // ---------------- ph1: DMA, JIT af(ks1), prefetch bfA(ks0 t+1),
      //                  MFMA ks1 ----
      if (t == 6 && more) {
#pragma unroll
        for (int i = 0; i < 3; ++i)
          dma16(aG[i] + (cc + 1) * 64, &As[(cc + 1) & 1][aL[i]]);
      }
      if (t < 6 || more) {   // j+3 < NT
        const char* bsrc = bG + (size_t)(j + 3) * 16384;
        char* bdst = smem + 24576 + (t % 3) * 16384 + bL;
#pragma unroll
        for (int i = 0; i < 4; ++i) dma16(bsrc + i * 1024, bdst + i * 1024);
      }
#pragma unroll
      for (int s = 0; s < 2; ++s) {
        int px = pxA + s * 36 + D;
        int a = px * 64 + (((2 + khalf) << 4) ^ (((px >> 1) & 3) << 4));
        af[s] = *(const half8*)(Ab + a);
      }
      if (t < 8 || more) {   // j+1 < NT
        const char* Bbn = smem + 24576 + ((t + 1) % 3) * 16384;
#pragma unroll
        for (int nt = 0; nt < 4; ++nt)
          bfA[nt] = *(const half8*)(Bbn + bo[nt]);
      }
      __builtin_amdgcn_sched_barrier(0);
      __builtin_amdgcn_s_setprio(1);
#pragma unroll
      for (int s = 0; s < 2; ++s)
#pragma unroll
        for (int nt = 0; nt < 4; ++nt)
          acc[s][nt] = __builtin_amdgcn_mfma_f32_32x32x16_f16(
              af[s], bfB[nt], acc[s][nt], 0, 0, 0);
      __builtin_amdgcn_s_setprio(0);
      // no tap-end sync: buffers touched next tap are guarded by that
      // tap's mid-tap barrier.
    }
  }
  __syncthreads();   // WAR: epilogue Qs overlays As/Bs (all waves' reads done)

  // ---- epilogue: bias+relu, stage to LDS [px][264], coalesced stores ----
  // C/D: col = lane&31, row = (r&3) + 8*(r>>2) + 4*(lane>>5)
#pragma unroll
  for (int s = 0; s < 2; ++s)
#pragma unroll
    for (int nt = 0; nt < 4; ++nt) {
      int n = nwave * 128 + nt * 32 + l31;
      float bn = bias[n];
#pragma unroll
      for (int r = 0; r < 16; ++r) {
        int mrow = (r & 3) + 8 * (r >> 2) + 4 * khalf;
        int p = (mwave * 4 + s * 2 + (mrow >> 4)) * 16 + (mrow & 15);
        Qs[p * 264 + n] = (_Float16)fmaxf(acc[s][nt][r] + bn, 0.f);
      }
    }
  __syncthreads();
  {
    _Float16* gout = actout + (((size_t)(b * 65536 + y0 * 256 + x0)) << 8);
#pragma unroll
    for (int i = 0; i < 16; ++i) {
      int f = tid + (i << 8);
      int p = f >> 5, o = f & 31;
      half8 v = *(const half8*)&Qs[p * 264 + o * 8];
      *(half8*)(gout + (((p >> 4) * 256 + (p & 15)) << 8) + o * 8) = v;
    }
  }
}

// ---------------------------------------------------------------------------
// Head, all 4 batches in one dispatch. One px per thread, all fp32 VALU;
// wmu2/lgb/label wave-uniform -> scalar loads. grid 1024.
// ---------------------------------------------------------------------------
__global__ __launch_bounds__(256) void k_head(
    const _Float16* __restrict__ a2_0, const _Float16* __restrict__ a2_1,
    const _Float16* __restrict__ a2_2, const _Float16* __restrict__ a2_3,
    const float* __restrict__ wmu2, const float* __restrict__ lgb,
    const float* __restrict__ label, float* __restrict__ out) {
  int b = blockIdx.x >> 8;
  int px = (blockIdx.x & 255) * 256 + threadIdx.x;
  const _Float16* base = (b == 0) ? a2_0 : (b == 1) ? a2_1
                       : (b == 2) ? a2_2 : a2_3;
  const half8* ap = (const half8*)(base + ((size_t)px << 8));
  float cr[16];
#pragma unroll
  for (int k = 0; k < 16; ++k) cr[k] = lgb[k];
#pragma unroll 2
  for (int cc = 0; cc < 32; ++cc) {
    half8 h = ap[cc];
    float a0 = (float)h[0], a1 = (float)h[1], a2 = (float)h[2],
          a3 = (float)h[3], a4 = (float)h[4], a5 = (float)h[5],
          a6 = (float)h[6], a7 = (float)h[7];
#pragma unroll
    for (int k = 0; k < 16; ++k) {
      const float* w = wmu2 + (k << 8) + (cc << 3);
      float c0 = cr[k];
      c0 = fmaf(a0, w[0], c0);
      c0 = fmaf(a1, w[1], c0);
      c0 = fmaf(a2, w[2], c0);
      c0 = fmaf(a3, w[3], c0);
      c0 = fmaf(a4, w[4], c0);
      c0 = fmaf(a5, w[5], c0);
      c0 = fmaf(a6, w[6], c0);
      c0 = fmaf(a7, w[7], c0);
      cr[k] = c0;
    }
  }
  float mx = cr[0];
#pragma unroll
  for (int k = 1; k < 16; ++k) mx = fmaxf(mx, cr[k]);
  float num = 0.f, den = 0.f;
#pragma unroll
  for (int k = 0; k < 16; ++k) {
    float e = __expf(cr[k] - mx);
    num = fmaf(e, label[k], num);
    den += e;
  }
  out[(size_t)b * 65536 + px] = num / den;
}

// ---------------------------------------------------------------------------
extern "C" void kernel_launch(void* const* d_in, const int* in_sizes, int n_in,
                              void* d_out, int out_size, void* d_ws, size_t ws_size,
                              hipStream_t stream) {
  const float* x  = (const float*)d_in[0];
  const float* w1 = (const float*)d_in[1];
  const float* b1 = (const float*)d_in[2];
  const float* w2 = (const float*)d_in[3];
  const float* b2 = (const float*)d_in[4];
  const float* w3 = (const float*)d_in[5];
  const float* b3 = (const float*)d_in[6];
  const float* mu = (const float*)d_in[7];
  const float* label = (const float*)d_in[8];
  float* out = (float*)d_out;

  char* ws = (char*)d_ws;
  _Float16* w1r  = (_Float16*)(ws + OFF_W1R);
  _Float16* w2r  = (_Float16*)(ws + OFF_W2R);
  float*    wmu2 = (float*)   (ws + OFF_WMU);
  float*    lgb  = (float*)   (ws + OFF_LGB);
  _Float16* act0 = (_Float16*)(ws + OFF_ACT0);   // [4][HW][64], 32 MB
  _Float16* act1 = (_Float16*)(ws + OFF_ACT1);   // [4][HW][256], 128 MB
  float*    wpart = (float*)  (ws + OFF_ACT1);   // 131 KB, dead before conv1

  _Float16* a2d[4] = {
    (_Float16*)(ws + OFF_ACT0),
    act1 + 0 * (size_t)65536 * 256,
    act1 + 1 * (size_t)65536 * 256,
    act1 + 2 * (size_t)65536 * 256
  };

  k_prep<<<3024, 256, 0, stream>>>(w1, w2, w3, b3, mu, w1r, w2r, wpart, lgb);
  k_prep2<<<16, 256, 0, stream>>>(wpart, wmu2);
  k_t0<<<4096, 256, 0, stream>>>(x, act0);
  k_conv<64><<<2048, 256, 0, stream>>>(act0, (const char*)w1r, b1, act1);
  for (int b = 0; b < BB; ++b)
    k_conv<256><<<512, 256, 0, stream>>>(act1 + (size_t)b * 65536 * 256,
                                         (const char*)w2r, b2, a2d[b]);
  k_head<<<1024, 256, 0, stream>>>(a2d[0], a2d[1], a2d[2], a2d[3],
                                   wmu2, lgb, label, out);
}